// Round 3
// baseline (429.119 us; speedup 1.0000x reference)
//
#include <hip/hip_runtime.h>
#include <math.h>

#define Bn  65536
#define Dn  512
#define Kn  64
#define H1n 256
#define H2n 128
#define BM  64   // rows per block

typedef short bf16x8 __attribute__((ext_vector_type(8)));
typedef float floatx4 __attribute__((ext_vector_type(4)));

__device__ __forceinline__ unsigned short f2bf(float f) {
    unsigned u = __builtin_bit_cast(unsigned, f);
    u += 0x7FFF + ((u >> 16) & 1);   // round-to-nearest-even
    return (unsigned short)(u >> 16);
}

// ---- prep: weights -> bf16 FRAGMENT-MAJOR layout Bf[t][ks][lane][8] ----
// so a wave's B-fragment load is 64 lanes x 16B fully contiguous (1KB).
// value at (t,ks,lane=quad*16+lrow,j) = W[k = ks*32+quad*8+j][n = t*16+lrow]
// ws elems: W1f @0 (131072), Tf @131072 (32768), W2f @163840 (32768), W3f @196608 (8192)
__global__ __launch_bounds__(256)
void prep_k(const float* __restrict__ W1, const float* __restrict__ W2,
            const float* __restrict__ W3, const float* __restrict__ Th,
            unsigned short* __restrict__ ws, float* __restrict__ out)
{
    const int gid = blockIdx.x * 256 + threadIdx.x;
    if (gid == 0) out[0] = 0.0f;
    if (gid < 131072) {                         // W1f: t<16, KS=16, N=256
        const int j = gid & 7, lane = (gid >> 3) & 63;
        const int ks = (gid >> 9) & 15, t = gid >> 13;
        const int k = ks * 32 + (lane >> 4) * 8 + j, n = t * 16 + (lane & 15);
        ws[gid] = f2bf(W1[k * H1n + n]);
    } else if (gid < 163840) {                  // Tf: t<4, KS=16, N=64
        const int i = gid - 131072;
        const int j = i & 7, lane = (i >> 3) & 63;
        const int ks = (i >> 9) & 15, t = i >> 13;
        const int k = ks * 32 + (lane >> 4) * 8 + j, n = t * 16 + (lane & 15);
        ws[gid] = f2bf(Th[k * Kn + n]);
    } else if (gid < 196608) {                  // W2f: t<8, KS=8, N=128
        const int i = gid - 163840;
        const int j = i & 7, lane = (i >> 3) & 63;
        const int ks = (i >> 9) & 7, t = i >> 12;
        const int k = ks * 32 + (lane >> 4) * 8 + j, n = t * 16 + (lane & 15);
        ws[gid] = f2bf(W2[k * H2n + n]);
    } else if (gid < 204800) {                  // W3f: t<4, KS=4, N=64
        const int i = gid - 196608;
        const int j = i & 7, lane = (i >> 3) & 63;
        const int ks = (i >> 9) & 3, t = i >> 11;
        const int k = ks * 32 + (lane >> 4) * 8 + j, n = t * 16 + (lane & 15);
        ws[gid] = f2bf(W3[k * Kn + n]);
    }
}

// LDS (49152 B -> 3 blocks/CU):
//  [0,16384):     x k-chunk (64 rows x 16 chunks of 16B, XOR swizzle); later xt f32[64][64]
//  [16384,49152): h1A (64 rows x 32 chunks); later h2A @16384 (16KB) + lg f32[64][64] @32768
__global__ __launch_bounds__(256, 3)
void llp_mfma(const float* __restrict__ x,
              const float* __restrict__ label,
              const float* __restrict__ u,
              const float* __restrict__ b1, const float* __restrict__ b2,
              const float* __restrict__ b3,
              const unsigned short* __restrict__ W1f,
              const unsigned short* __restrict__ Tf,
              const unsigned short* __restrict__ W2f,
              const unsigned short* __restrict__ W3f,
              const int* __restrict__ epoch_p,
              float* __restrict__ out)
{
    __shared__ char smem[49152];

    const int tid  = threadIdx.x;
    const int row0 = blockIdx.x * BM;
    const int w    = tid >> 6;
    const int lane = tid & 63;
    const int lrow = lane & 15;
    const int quad = lane >> 4;
    const int rg   = w >> 1;      // row half: rows rg*32 .. +31 (2 tiles)
    const int ch   = w & 1;       // col half

    floatx4 acc[2][8];            // h1: 2 row tiles x 8 col tiles
    floatx4 xtacc[2][2];          // xt: 2 row tiles x 2 col tiles
    #pragma unroll
    for (int t = 0; t < 8; ++t) {
        const float bv = b1[ch * 128 + t * 16 + lrow];
        acc[0][t] = (floatx4){bv, bv, bv, bv};
        acc[1][t] = (floatx4){bv, bv, bv, bv};
    }
    xtacc[0][0] = xtacc[0][1] = xtacc[1][0] = xtacc[1][1] = (floatx4){0.f,0.f,0.f,0.f};

    const float4* xg4 = (const float4*)(x + (size_t)row0 * Dn);

    // ---- x in 4 k-chunks of 128; accumulate h1 and xt ----
    for (int kc = 0; kc < 4; ++kc) {
        if (kc) __syncthreads();               // prev chunk fully consumed
        #pragma unroll
        for (int i = 0; i < 8; ++i) {
            const int f   = tid + i * 256;     // 0..2047 float4 of this chunk
            const int row = f >> 5, c4 = f & 31;
            const float4 v = xg4[row * 128 + kc * 32 + c4];
            const int kb = c4 >> 1, half = c4 & 1;
            ushort4 o;
            o.x = f2bf(v.x); o.y = f2bf(v.y); o.z = f2bf(v.z); o.w = f2bf(v.w);
            *(ushort4*)(smem + (((row << 4) + (kb ^ (row & 7))) << 4) + (half << 3)) = o;
        }
        __syncthreads();

        #pragma unroll
        for (int ksl = 0; ksl < 4; ++ksl) {
            const int ks = kc * 4 + ksl;
            bf16x8 a[2];
            #pragma unroll
            for (int rt = 0; rt < 2; ++rt) {
                const int r = rg * 32 + rt * 16 + lrow;
                a[rt] = *(const bf16x8*)(smem + (((r << 4) + ((ksl * 4 + quad) ^ (r & 7))) << 4));
            }
            #pragma unroll
            for (int t = 0; t < 8; ++t) {
                const bf16x8 b = *(const bf16x8*)(W1f + ((((ch * 8 + t) * 16 + ks) * 64 + lane) << 3));
                acc[0][t] = __builtin_amdgcn_mfma_f32_16x16x32_bf16(a[0], b, acc[0][t], 0, 0, 0);
                acc[1][t] = __builtin_amdgcn_mfma_f32_16x16x32_bf16(a[1], b, acc[1][t], 0, 0, 0);
            }
            #pragma unroll
            for (int t = 0; t < 2; ++t) {
                const bf16x8 b = *(const bf16x8*)(Tf + ((((ch * 2 + t) * 16 + ks) * 64 + lane) << 3));
                xtacc[0][t] = __builtin_amdgcn_mfma_f32_16x16x32_bf16(a[0], b, xtacc[0][t], 0, 0, 0);
                xtacc[1][t] = __builtin_amdgcn_mfma_f32_16x16x32_bf16(a[1], b, xtacc[1][t], 0, 0, 0);
            }
        }
    }

    // ---- h1 -> bf16 A-layout @16384 (no conflict with x buffer) ----
    #pragma unroll
    for (int rt = 0; rt < 2; ++rt) {
        #pragma unroll
        for (int t = 0; t < 8; ++t) {
            const int col = ch * 128 + t * 16 + lrow;
            #pragma unroll
            for (int g = 0; g < 4; ++g) {
                const int orow = rg * 32 + rt * 16 + quad * 4 + g;
                *(unsigned short*)(smem + 16384 +
                    ((orow * 32 + ((col >> 3) ^ (orow & 7))) << 4) + ((col & 7) << 1))
                    = f2bf(fmaxf(acc[rt][t][g], 0.0f));
            }
        }
    }
    __syncthreads();   // x dead, h1A complete

    // xt f32 -> @0
    {
        float* xtf = (float*)smem;
        #pragma unroll
        for (int rt = 0; rt < 2; ++rt)
            #pragma unroll
            for (int t = 0; t < 2; ++t) {
                const int col = ch * 32 + t * 16 + lrow;
                #pragma unroll
                for (int g = 0; g < 4; ++g)
                    xtf[(rg * 32 + rt * 16 + quad * 4 + g) * 64 + col] = xtacc[rt][t][g];
            }
    }

    // ---- h2 = relu(h1 @ W2 + b2) ----
    floatx4 acc2[2][4];
    #pragma unroll
    for (int t = 0; t < 4; ++t) {
        const float bv = b2[ch * 64 + t * 16 + lrow];
        acc2[0][t] = (floatx4){bv, bv, bv, bv};
        acc2[1][t] = (floatx4){bv, bv, bv, bv};
    }
    #pragma unroll
    for (int ks = 0; ks < 8; ++ks) {
        bf16x8 a[2];
        #pragma unroll
        for (int rt = 0; rt < 2; ++rt) {
            const int r = rg * 32 + rt * 16 + lrow;
            a[rt] = *(const bf16x8*)(smem + 16384 + ((r * 32 + ((ks * 4 + quad) ^ (r & 7))) << 4));
        }
        #pragma unroll
        for (int t = 0; t < 4; ++t) {
            const bf16x8 b = *(const bf16x8*)(W2f + ((((ch * 4 + t) * 8 + ks) * 64 + lane) << 3));
            acc2[0][t] = __builtin_amdgcn_mfma_f32_16x16x32_bf16(a[0], b, acc2[0][t], 0, 0, 0);
            acc2[1][t] = __builtin_amdgcn_mfma_f32_16x16x32_bf16(a[1], b, acc2[1][t], 0, 0, 0);
        }
    }
    __syncthreads();   // all h1A reads done

    // h2 -> bf16 A-layout @16384 (16KB)
    #pragma unroll
    for (int rt = 0; rt < 2; ++rt)
        #pragma unroll
        for (int t = 0; t < 4; ++t) {
            const int col = ch * 64 + t * 16 + lrow;
            #pragma unroll
            for (int g = 0; g < 4; ++g) {
                const int orow = rg * 32 + rt * 16 + quad * 4 + g;
                *(unsigned short*)(smem + 16384 +
                    ((orow * 16 + ((col >> 3) ^ (orow & 7))) << 4) + ((col & 7) << 1))
                    = f2bf(fmaxf(acc2[rt][t][g], 0.0f));
            }
        }
    __syncthreads();   // h2A complete

    // ---- logits = h2 @ W3 + b3 ----
    floatx4 acc3[2][2];
    #pragma unroll
    for (int t = 0; t < 2; ++t) {
        const float bv = b3[ch * 32 + t * 16 + lrow];
        acc3[0][t] = (floatx4){bv, bv, bv, bv};
        acc3[1][t] = (floatx4){bv, bv, bv, bv};
    }
    #pragma unroll
    for (int ks = 0; ks < 4; ++ks) {
        bf16x8 a[2];
        #pragma unroll
        for (int rt = 0; rt < 2; ++rt) {
            const int r = rg * 32 + rt * 16 + lrow;
            a[rt] = *(const bf16x8*)(smem + 16384 + ((r * 16 + ((ks * 4 + quad) ^ (r & 7))) << 4));
        }
        #pragma unroll
        for (int t = 0; t < 2; ++t) {
            const bf16x8 b = *(const bf16x8*)(W3f + ((((ch * 2 + t) * 4 + ks) * 64 + lane) << 3));
            acc3[0][t] = __builtin_amdgcn_mfma_f32_16x16x32_bf16(a[0], b, acc3[0][t], 0, 0, 0);
            acc3[1][t] = __builtin_amdgcn_mfma_f32_16x16x32_bf16(a[1], b, acc3[1][t], 0, 0, 0);
        }
    }
    // logits f32 -> @32768 (h1A upper half, dead)
    {
        float* lgf = (float*)(smem + 32768);
        #pragma unroll
        for (int rt = 0; rt < 2; ++rt)
            #pragma unroll
            for (int t = 0; t < 2; ++t) {
                const int col = ch * 32 + t * 16 + lrow;
                #pragma unroll
                for (int g = 0; g < 4; ++g)
                    lgf[(rg * 32 + rt * 16 + quad * 4 + g) * 64 + col] = acc3[rt][t][g];
            }
    }
    __syncthreads();

    // ---- softmax + weighted sum + loss: wave w -> rows w*16..+15, lane == k ----
    {
        const float* xtf = (const float*)smem;
        const float* lgf = (const float*)(smem + 32768);
        const int ep = *epoch_p;
        const float tmp = 10.0f * powf(0.01f, (float)ep * 0.001f);
        const float inv_temp = 1.0f / fmaxf(0.1f, tmp);

        float partial = 0.0f;
        #pragma unroll
        for (int rr = 0; rr < 16; ++rr) {
            const int rw  = w * 16 + rr;
            const int row = row0 + rw;
            const float uu = u[(size_t)row * Kn + lane];
            const float g  = -logf(-logf(uu));
            float s = (lgf[rw * 64 + lane] + g) * inv_temp;
            float m = s;
            #pragma unroll
            for (int off = 32; off > 0; off >>= 1)
                m = fmaxf(m, __shfl_xor(m, off));
            const float e = expf(s - m);
            float sum = e;
            #pragma unroll
            for (int off = 32; off > 0; off >>= 1)
                sum += __shfl_xor(sum, off);
            float v = (e / sum) * xtf[rw * 64 + lane];
            #pragma unroll
            for (int off = 32; off > 0; off >>= 1)
                v += __shfl_xor(v, off);
            if (lane == 0) {
                const float diff = v - label[row];
                partial = fmaf(diff, diff, partial);
            }
        }
        if (lane == 0)
            atomicAdd(out, partial * (1.0f / (float)Bn));
    }
}

extern "C" void kernel_launch(void* const* d_in, const int* in_sizes, int n_in,
                              void* d_out, int out_size, void* d_ws, size_t ws_size,
                              hipStream_t stream) {
    const float* x      = (const float*)d_in[0];
    const float* label  = (const float*)d_in[1];
    const float* u      = (const float*)d_in[2];
    const float* W1     = (const float*)d_in[3];
    const float* b1     = (const float*)d_in[4];
    const float* W2     = (const float*)d_in[5];
    const float* b2     = (const float*)d_in[6];
    const float* W3     = (const float*)d_in[7];
    const float* b3     = (const float*)d_in[8];
    const float* thetas = (const float*)d_in[9];
    const int*   epoch  = (const int*)d_in[10];
    float* out = (float*)d_out;

    unsigned short* wsb = (unsigned short*)d_ws;
    prep_k<<<800, 256, 0, stream>>>(W1, W2, W3, thetas, wsb, out);
    llp_mfma<<<Bn / BM, 256, 0, stream>>>(x, label, u, b1, b2, b3,
                                          wsb, wsb + 131072, wsb + 163840, wsb + 196608,
                                          epoch, out);
}

// Round 4
// 410.292 us; speedup vs baseline: 1.0459x; 1.0459x over previous
//
#include <hip/hip_runtime.h>
#include <math.h>

#define Bn  65536
#define Dn  512
#define Kn  64
#define H1n 256
#define H2n 128
#define BM  32   // rows per block

typedef short bf16x8 __attribute__((ext_vector_type(8)));
typedef float floatx4 __attribute__((ext_vector_type(4)));

__device__ __forceinline__ unsigned short f2bf(float f) {
    unsigned u = __builtin_bit_cast(unsigned, f);
    u += 0x7FFF + ((u >> 16) & 1);   // round-to-nearest-even
    return (unsigned short)(u >> 16);
}

// ---- prep: fp32 weights -> bf16 FRAGMENT-MAJOR Bf[t][ks][lane][8] ----
// Source-major (coalesced reads, scattered 2B writes - only 400KB total).
// Bf element ((t*KS+ks)*64 + quad*16+lrow)*8 + j  =  W[ks*32+quad*8+j][t*16+lrow]
// ws elems: W1f @0 (131072, KS=16), Tf @131072 (32768, KS=16),
//           W2f @163840 (32768, KS=8), W3f @196608 (8192, KS=4)
__global__ __launch_bounds__(256)
void prep_k(const float* __restrict__ W1, const float* __restrict__ W2,
            const float* __restrict__ W3, const float* __restrict__ Th,
            unsigned short* __restrict__ ws, float* __restrict__ out)
{
    const int gid = blockIdx.x * 256 + threadIdx.x;
    if (gid == 0) out[0] = 0.0f;
    if (gid < 131072) {                       // W1 [512][256]
        const int s = gid, k = s >> 8, n = s & 255;
        const int dst = (((n >> 4) * 16 + (k >> 5)) * 64 + ((k >> 3) & 3) * 16 + (n & 15)) * 8 + (k & 7);
        ws[dst] = f2bf(W1[s]);
    } else if (gid < 163840) {                // thetas [512][64]
        const int s = gid - 131072, k = s >> 6, n = s & 63;
        const int dst = 131072 + (((n >> 4) * 16 + (k >> 5)) * 64 + ((k >> 3) & 3) * 16 + (n & 15)) * 8 + (k & 7);
        ws[dst] = f2bf(Th[s]);
    } else if (gid < 196608) {                // W2 [256][128]
        const int s = gid - 163840, k = s >> 7, n = s & 127;
        const int dst = 163840 + (((n >> 4) * 8 + (k >> 5)) * 64 + ((k >> 3) & 3) * 16 + (n & 15)) * 8 + (k & 7);
        ws[dst] = f2bf(W2[s]);
    } else if (gid < 204800) {                // W3 [128][64]
        const int s = gid - 196608, k = s >> 6, n = s & 63;
        const int dst = 196608 + (((n >> 4) * 4 + (k >> 5)) * 64 + ((k >> 3) & 3) * 16 + (n & 15)) * 8 + (k & 7);
        ws[dst] = f2bf(W3[s]);
    }
}

// LDS (49152 B -> 3 blocks/CU; 8 waves/block -> 24 waves/CU):
//  [0,32768):     phase1 xA: 32 rows x 64 chunks(16B), XOR-swizzled
//                 phase2+: xt f32[32][65] @0, lg f32[32][65] @8704, h2A @17408 (8KB)
//  [32768,49152): h1A: 32 rows x 32 chunks, XOR-swizzled
__global__ __launch_bounds__(512, 6)
void llp_mfma(const float* __restrict__ x,
              const float* __restrict__ label,
              const float* __restrict__ u,
              const float* __restrict__ b1, const float* __restrict__ b2,
              const float* __restrict__ b3,
              const unsigned short* __restrict__ W1f,
              const unsigned short* __restrict__ Tf,
              const unsigned short* __restrict__ W2f,
              const unsigned short* __restrict__ W3f,
              const int* __restrict__ epoch_p,
              float* __restrict__ out)
{
    __shared__ char smem[49152];

    const int tid  = threadIdx.x;
    const int row0 = blockIdx.x * BM;
    const int w    = tid >> 6;      // wave 0..7
    const int lane = tid & 63;
    const int lrow = lane & 15;
    const int quad = lane >> 4;

    // ---- prefetch u (4 rows/wave) + labels into registers (hide HBM latency) ----
    float upf[4], labpf[4];
    #pragma unroll
    for (int rr = 0; rr < 4; ++rr) {
        upf[rr]   = u[(size_t)(row0 + w * 4 + rr) * Kn + lane];
        labpf[rr] = label[row0 + w * 4 + rr];
    }

    // ---- stage x tile (one shot): 4096 float4, 8 per thread ----
    {
        const float4* xg4 = (const float4*)(x + (size_t)row0 * Dn);
        #pragma unroll
        for (int i = 0; i < 8; ++i) {
            const int f = tid + i * 512;           // float4 idx 0..4095
            const float4 v = xg4[f];
            const int row = f >> 7, c4 = f & 127;
            const int kb = c4 >> 1, half = c4 & 1;
            ushort4 o;
            o.x = f2bf(v.x); o.y = f2bf(v.y); o.z = f2bf(v.z); o.w = f2bf(v.w);
            *(ushort4*)(smem + ((row * 64 + (kb ^ (row & 7))) << 4) + (half << 3)) = o;
        }
    }
    __syncthreads();

    const int ct0 = 2 * w, ct1 = 2 * w + 1;   // h1 col tiles (0..15)
    const int rtx = w >> 2, ctx = w & 3;      // xt assignment

    // ---- h1 = relu(x@W1+b1) [2 rt x 2 ct per wave] and xt = x@thetas [1 tile] ----
    floatx4 acc[2][2], xtac;
    #pragma unroll
    for (int i = 0; i < 2; ++i) {
        const float bv = b1[(2 * w + i) * 16 + lrow];
        acc[0][i] = (floatx4){bv, bv, bv, bv};
        acc[1][i] = (floatx4){bv, bv, bv, bv};
    }
    xtac = (floatx4){0.f, 0.f, 0.f, 0.f};

    #pragma unroll 4
    for (int ks = 0; ks < 16; ++ks) {
        const int sw = (ks * 4 + quad) ^ (lrow & 7);   // (16+lrow)&7 == lrow&7
        const bf16x8 a0 = *(const bf16x8*)(smem + ((lrow * 64 + sw) << 4));
        const bf16x8 a1 = *(const bf16x8*)(smem + (((16 + lrow) * 64 + sw) << 4));
        const bf16x8 bw0 = *(const bf16x8*)(W1f + (((ct0 * 16 + ks) * 64 + lane) << 3));
        const bf16x8 bw1 = *(const bf16x8*)(W1f + (((ct1 * 16 + ks) * 64 + lane) << 3));
        const bf16x8 bt  = *(const bf16x8*)(Tf  + (((ctx * 16 + ks) * 64 + lane) << 3));
        acc[0][0] = __builtin_amdgcn_mfma_f32_16x16x32_bf16(a0, bw0, acc[0][0], 0, 0, 0);
        acc[1][0] = __builtin_amdgcn_mfma_f32_16x16x32_bf16(a1, bw0, acc[1][0], 0, 0, 0);
        acc[0][1] = __builtin_amdgcn_mfma_f32_16x16x32_bf16(a0, bw1, acc[0][1], 0, 0, 0);
        acc[1][1] = __builtin_amdgcn_mfma_f32_16x16x32_bf16(a1, bw1, acc[1][1], 0, 0, 0);
        xtac = __builtin_amdgcn_mfma_f32_16x16x32_bf16(rtx ? a1 : a0, bt, xtac, 0, 0, 0);
    }

    // h1 -> bf16 A-layout @32768 (separate region, no race with xA reads)
    #pragma unroll
    for (int rt = 0; rt < 2; ++rt)
        #pragma unroll
        for (int i = 0; i < 2; ++i) {
            const int col = (2 * w + i) * 16 + lrow;
            #pragma unroll
            for (int g = 0; g < 4; ++g) {
                const int orow = rt * 16 + quad * 4 + g;
                *(unsigned short*)(smem + 32768 +
                    ((orow * 32 + ((col >> 3) ^ (orow & 7))) << 4) + ((col & 7) << 1))
                    = f2bf(fmaxf(acc[rt][i][g], 0.0f));
            }
        }
    __syncthreads();   // xA dead; h1A complete

    // xt f32 -> @0 [32][65] (pad 65 breaks bank aliasing on stores)
    {
        float* xtf = (float*)smem;
        #pragma unroll
        for (int g = 0; g < 4; ++g)
            xtf[(rtx * 16 + quad * 4 + g) * 65 + ctx * 16 + lrow] = xtac[g];
    }

    // ---- h2 = relu(h1@W2+b2): wave -> rt=w>>2, ct in {2*(w&3), +1} of 8 ----
    const int rt2 = w >> 2, c2a = 2 * (w & 3), c2b = c2a + 1;
    floatx4 acc2[2];
    {
        const float bva = b2[c2a * 16 + lrow], bvb = b2[c2b * 16 + lrow];
        acc2[0] = (floatx4){bva, bva, bva, bva};
        acc2[1] = (floatx4){bvb, bvb, bvb, bvb};
    }
    #pragma unroll
    for (int ks = 0; ks < 8; ++ks) {
        const int r = rt2 * 16 + lrow;
        const bf16x8 a = *(const bf16x8*)(smem + 32768 +
                            ((r * 32 + ((ks * 4 + quad) ^ (lrow & 7))) << 4));
        const bf16x8 ba = *(const bf16x8*)(W2f + (((c2a * 8 + ks) * 64 + lane) << 3));
        const bf16x8 bb = *(const bf16x8*)(W2f + (((c2b * 8 + ks) * 64 + lane) << 3));
        acc2[0] = __builtin_amdgcn_mfma_f32_16x16x32_bf16(a, ba, acc2[0], 0, 0, 0);
        acc2[1] = __builtin_amdgcn_mfma_f32_16x16x32_bf16(a, bb, acc2[1], 0, 0, 0);
    }
    // h2 -> bf16 A-layout @17408 (8KB; region untouched since sync above)
    #pragma unroll
    for (int i = 0; i < 2; ++i) {
        const int col = (c2a + i) * 16 + lrow;
        #pragma unroll
        for (int g = 0; g < 4; ++g) {
            const int orow = rt2 * 16 + quad * 4 + g;
            *(unsigned short*)(smem + 17408 +
                ((orow * 16 + ((col >> 3) ^ (orow & 7))) << 4) + ((col & 7) << 1))
                = f2bf(fmaxf(acc2[i][g], 0.0f));
        }
    }
    __syncthreads();   // h2A complete

    // ---- logits = h2@W3+b3: wave -> rt=w>>2, ct=w&3 ----
    floatx4 acc3;
    {
        const float bv = b3[ctx * 16 + lrow];
        acc3 = (floatx4){bv, bv, bv, bv};
    }
    #pragma unroll
    for (int ks = 0; ks < 4; ++ks) {
        const int r = rtx * 16 + lrow;
        const bf16x8 a = *(const bf16x8*)(smem + 17408 +
                            ((r * 16 + ((ks * 4 + quad) ^ (lrow & 7))) << 4));
        const bf16x8 b = *(const bf16x8*)(W3f + (((ctx * 4 + ks) * 64 + lane) << 3));
        acc3 = __builtin_amdgcn_mfma_f32_16x16x32_bf16(a, b, acc3, 0, 0, 0);
    }
    {
        float* lgf = (float*)(smem + 8704);   // [32][65]
        #pragma unroll
        for (int g = 0; g < 4; ++g)
            lgf[(rtx * 16 + quad * 4 + g) * 65 + ctx * 16 + lrow] = acc3[g];
    }
    __syncthreads();

    // ---- softmax + weighted sum + loss: wave w -> rows w*4..+3, lane == k ----
    {
        const float* xtf = (const float*)smem;
        const float* lgf = (const float*)(smem + 8704);
        const int ep = *epoch_p;
        const float tmp = 10.0f * powf(0.01f, (float)ep * 0.001f);
        const float inv_temp = 1.0f / fmaxf(0.1f, tmp);

        float partial = 0.0f;
        #pragma unroll
        for (int rr = 0; rr < 4; ++rr) {
            const int rw = w * 4 + rr;
            const float g = -logf(-logf(upf[rr]));
            float s = (lgf[rw * 65 + lane] + g) * inv_temp;
            float m = s;
            #pragma unroll
            for (int off = 32; off > 0; off >>= 1)
                m = fmaxf(m, __shfl_xor(m, off));
            const float e = expf(s - m);
            float sum = e;
            #pragma unroll
            for (int off = 32; off > 0; off >>= 1)
                sum += __shfl_xor(sum, off);
            float v = (e / sum) * xtf[rw * 65 + lane];
            #pragma unroll
            for (int off = 32; off > 0; off >>= 1)
                v += __shfl_xor(v, off);
            if (lane == 0) {
                const float diff = v - labpf[rr];
                partial = fmaf(diff, diff, partial);
            }
        }
        if (lane == 0)
            atomicAdd(out, partial * (1.0f / (float)Bn));
    }
}

extern "C" void kernel_launch(void* const* d_in, const int* in_sizes, int n_in,
                              void* d_out, int out_size, void* d_ws, size_t ws_size,
                              hipStream_t stream) {
    const float* x      = (const float*)d_in[0];
    const float* label  = (const float*)d_in[1];
    const float* u      = (const float*)d_in[2];
    const float* W1     = (const float*)d_in[3];
    const float* b1     = (const float*)d_in[4];
    const float* W2     = (const float*)d_in[5];
    const float* b2     = (const float*)d_in[6];
    const float* W3     = (const float*)d_in[7];
    const float* b3     = (const float*)d_in[8];
    const float* thetas = (const float*)d_in[9];
    const int*   epoch  = (const int*)d_in[10];
    float* out = (float*)d_out;

    unsigned short* wsb = (unsigned short*)d_ws;
    prep_k<<<800, 256, 0, stream>>>(W1, W2, W3, thetas, wsb, out);
    llp_mfma<<<Bn / BM, 512, 0, stream>>>(x, label, u, b1, b2, b3,
                                          wsb, wsb + 131072, wsb + 163840, wsb + 196608,
                                          epoch, out);
}

// Round 5
// 306.534 us; speedup vs baseline: 1.3999x; 1.3385x over previous
//
#include <hip/hip_runtime.h>
#include <math.h>

#define Bn  65536
#define Dn  512
#define Kn  64
#define H1n 256
#define H2n 128
#define BM  16   // rows per block (4096 blocks, 4 waves each)

typedef short bf16x8 __attribute__((ext_vector_type(8)));
typedef float floatx4 __attribute__((ext_vector_type(4)));

__device__ __forceinline__ unsigned short f2bf(float f) {
    unsigned u = __builtin_bit_cast(unsigned, f);
    u += 0x7FFF + ((u >> 16) & 1);   // round-to-nearest-even
    return (unsigned short)(u >> 16);
}

// ---- prep: fp32 weights -> bf16 FRAGMENT-MAJOR Bf[t][ks][lane][8] ----
// Bf element ((t*KS+ks)*64 + quad*16+lrow)*8 + j  =  W[ks*32+quad*8+j][t*16+lrow]
// ws (ushort elems): W1f @0 (131072, KS=16), Tf @131072 (32768, KS=16),
//                    W2f @163840 (32768, KS=8), W3f @196608 (8192, KS=4)
// partials (float)  @ushort offset 204800 (byte 409600), 16384 entries
__global__ __launch_bounds__(256)
void prep_k(const float* __restrict__ W1, const float* __restrict__ W2,
            const float* __restrict__ W3, const float* __restrict__ Th,
            unsigned short* __restrict__ ws)
{
    const int gid = blockIdx.x * 256 + threadIdx.x;
    if (gid < 131072) {                       // W1 [512][256]
        const int s = gid, k = s >> 8, n = s & 255;
        const int dst = (((n >> 4) * 16 + (k >> 5)) * 64 + ((k >> 3) & 3) * 16 + (n & 15)) * 8 + (k & 7);
        ws[dst] = f2bf(W1[s]);
    } else if (gid < 163840) {                // thetas [512][64]
        const int s = gid - 131072, k = s >> 6, n = s & 63;
        const int dst = 131072 + (((n >> 4) * 16 + (k >> 5)) * 64 + ((k >> 3) & 3) * 16 + (n & 15)) * 8 + (k & 7);
        ws[dst] = f2bf(Th[s]);
    } else if (gid < 196608) {                // W2 [256][128]
        const int s = gid - 163840, k = s >> 7, n = s & 127;
        const int dst = 163840 + (((n >> 4) * 8 + (k >> 5)) * 64 + ((k >> 3) & 3) * 16 + (n & 15)) * 8 + (k & 7);
        ws[dst] = f2bf(W2[s]);
    } else if (gid < 204800) {                // W3 [128][64]
        const int s = gid - 196608, k = s >> 6, n = s & 63;
        const int dst = 196608 + (((n >> 4) * 4 + (k >> 5)) * 64 + ((k >> 3) & 3) * 16 + (n & 15)) * 8 + (k & 7);
        ws[dst] = f2bf(W3[s]);
    }
}

// ---- final reduce: sum 16384 wave partials -> out[0] (no atomics anywhere) ----
__global__ __launch_bounds__(1024)
void reduce_k(const float* __restrict__ p, float* __restrict__ out)
{
    __shared__ float sred[16];
    const int tid = threadIdx.x;
    float s = 0.f;
    #pragma unroll
    for (int i = 0; i < 16; ++i) s += p[tid + i * 1024];
    #pragma unroll
    for (int off = 32; off > 0; off >>= 1) s += __shfl_xor(s, off);
    if ((tid & 63) == 0) sred[tid >> 6] = s;
    __syncthreads();
    if (tid < 64) {
        float v = (tid < 16) ? sred[tid] : 0.f;
        #pragma unroll
        for (int off = 8; off > 0; off >>= 1) v += __shfl_xor(v, off);
        if (tid == 0) out[0] = v * (1.0f / (float)Bn);
    }
}

// LDS 28672 B -> 5 blocks/CU (20 waves/CU):
//  [0,16384):     phase1 xA: 16 rows x 64 chunks(16B), XOR-swizzled
//                 phase2+: xt f32[16][68] @0 (4352), lg f32[16][68] @8192 (4352)
//  [16384,24576): h1A: 16 rows x 32 chunks
//  [24576,28672): h2A: 16 rows x 16 chunks
__global__ __launch_bounds__(256, 4)
void llp_mfma(const float* __restrict__ x,
              const float* __restrict__ label,
              const float* __restrict__ u,
              const float* __restrict__ b1, const float* __restrict__ b2,
              const float* __restrict__ b3,
              const unsigned short* __restrict__ W1f,
              const unsigned short* __restrict__ Tf,
              const unsigned short* __restrict__ W2f,
              const unsigned short* __restrict__ W3f,
              const int* __restrict__ epoch_p,
              float* __restrict__ partials)
{
    __shared__ char smem[28672];

    const int tid  = threadIdx.x;
    const int row0 = blockIdx.x * BM;
    const int w    = tid >> 6;      // wave 0..3
    const int lane = tid & 63;
    const int lrow = lane & 15;
    const int quad = lane >> 4;

    // ---- prefetch u (4 rows/wave) + labels (hide HBM latency behind staging) ----
    float upf[4], labpf[4];
    #pragma unroll
    for (int rr = 0; rr < 4; ++rr) {
        upf[rr]   = u[(size_t)(row0 + w * 4 + rr) * Kn + lane];
        labpf[rr] = label[row0 + w * 4 + rr];
    }

    // ---- stage x tile: 2048 float4, 8 per thread, coalesced ----
    {
        const float4* xg4 = (const float4*)(x + (size_t)row0 * Dn);
        #pragma unroll
        for (int i = 0; i < 8; ++i) {
            const int f = tid + i * 256;           // float4 idx 0..2047
            const float4 v = xg4[f];
            const int row = f >> 7, c4 = f & 127;  // 128 float4 per row
            const int kb = c4 >> 1, half = c4 & 1;
            ushort4 o;
            o.x = f2bf(v.x); o.y = f2bf(v.y); o.z = f2bf(v.z); o.w = f2bf(v.w);
            *(ushort4*)(smem + ((row * 64 + (kb ^ (row & 7))) << 4) + (half << 3)) = o;
        }
    }
    __syncthreads();

    // ---- phase 1: h1 = relu(x@W1+b1) (4 col tiles/wave) + xt = x@thetas (1 tile) ----
    const int ct0 = w * 4;
    floatx4 acc[4], xtac;
    #pragma unroll
    for (int t = 0; t < 4; ++t) {
        const float bv = b1[(ct0 + t) * 16 + lrow];
        acc[t] = (floatx4){bv, bv, bv, bv};
    }
    xtac = (floatx4){0.f, 0.f, 0.f, 0.f};

    #pragma unroll 4
    for (int ks = 0; ks < 16; ++ks) {
        const bf16x8 a = *(const bf16x8*)(smem +
                            ((lrow * 64 + ((ks * 4 + quad) ^ (lrow & 7))) << 4));
        #pragma unroll
        for (int t = 0; t < 4; ++t) {
            const bf16x8 b = *(const bf16x8*)(W1f + ((((ct0 + t) * 16 + ks) * 64 + lane) << 3));
            acc[t] = __builtin_amdgcn_mfma_f32_16x16x32_bf16(a, b, acc[t], 0, 0, 0);
        }
        const bf16x8 bt = *(const bf16x8*)(Tf + (((w * 16 + ks) * 64 + lane) << 3));
        xtac = __builtin_amdgcn_mfma_f32_16x16x32_bf16(a, bt, xtac, 0, 0, 0);
    }

    // h1 C-layout -> bf16 A-layout @16384
    #pragma unroll
    for (int t = 0; t < 4; ++t) {
        const int col = (ct0 + t) * 16 + lrow;
        #pragma unroll
        for (int g = 0; g < 4; ++g) {
            const int orow = quad * 4 + g;
            *(unsigned short*)(smem + 16384 +
                ((orow * 32 + ((col >> 3) ^ (orow & 7))) << 4) + ((col & 7) << 1))
                = f2bf(fmaxf(acc[t][g], 0.0f));
        }
    }
    __syncthreads();   // xA dead; h1A complete

    // xt f32 -> @0 [16][68]
    {
        float* xtf = (float*)smem;
        #pragma unroll
        for (int g = 0; g < 4; ++g)
            xtf[(quad * 4 + g) * 68 + w * 16 + lrow] = xtac[g];
    }

    // ---- h2 = relu(h1@W2+b2): 2 col tiles/wave ----
    const int c2 = w * 2;
    floatx4 acc2[2];
    #pragma unroll
    for (int i = 0; i < 2; ++i) {
        const float bv = b2[(c2 + i) * 16 + lrow];
        acc2[i] = (floatx4){bv, bv, bv, bv};
    }
    #pragma unroll
    for (int ks = 0; ks < 8; ++ks) {
        const bf16x8 a = *(const bf16x8*)(smem + 16384 +
                            ((lrow * 32 + ((ks * 4 + quad) ^ (lrow & 7))) << 4));
        #pragma unroll
        for (int i = 0; i < 2; ++i) {
            const bf16x8 b = *(const bf16x8*)(W2f + ((((c2 + i) * 8 + ks) * 64 + lane) << 3));
            acc2[i] = __builtin_amdgcn_mfma_f32_16x16x32_bf16(a, b, acc2[i], 0, 0, 0);
        }
    }
    #pragma unroll
    for (int i = 0; i < 2; ++i) {
        const int col = (c2 + i) * 16 + lrow;
        #pragma unroll
        for (int g = 0; g < 4; ++g) {
            const int orow = quad * 4 + g;
            *(unsigned short*)(smem + 24576 +
                ((orow * 16 + ((col >> 3) ^ (orow & 7))) << 4) + ((col & 7) << 1))
                = f2bf(fmaxf(acc2[i][g], 0.0f));
        }
    }
    __syncthreads();   // h2A complete (xt stores also done)

    // ---- logits = h2@W3+b3: 1 col tile/wave ----
    floatx4 acc3;
    {
        const float bv = b3[w * 16 + lrow];
        acc3 = (floatx4){bv, bv, bv, bv};
    }
    #pragma unroll
    for (int ks = 0; ks < 4; ++ks) {
        const bf16x8 a = *(const bf16x8*)(smem + 24576 +
                            ((lrow * 16 + ((ks * 4 + quad) ^ (lrow & 7))) << 4));
        const bf16x8 b = *(const bf16x8*)(W3f + (((w * 4 + ks) * 64 + lane) << 3));
        acc3 = __builtin_amdgcn_mfma_f32_16x16x32_bf16(a, b, acc3, 0, 0, 0);
    }
    {
        float* lgf = (float*)(smem + 8192);   // [16][68]
        #pragma unroll
        for (int g = 0; g < 4; ++g)
            lgf[(quad * 4 + g) * 68 + w * 16 + lrow] = acc3[g];
    }
    __syncthreads();

    // ---- softmax + weighted sum + loss partial: wave w -> rows w*4..+3 ----
    {
        const float* xtf = (const float*)smem;
        const float* lgf = (const float*)(smem + 8192);
        const int ep = *epoch_p;
        const float tmp = 10.0f * powf(0.01f, (float)ep * 0.001f);
        const float inv_temp = 1.0f / fmaxf(0.1f, tmp);

        float partial = 0.0f;
        #pragma unroll
        for (int rr = 0; rr < 4; ++rr) {
            const int rw = w * 4 + rr;
            const float g = -logf(-logf(upf[rr]));
            float s = (lgf[rw * 68 + lane] + g) * inv_temp;
            float m = s;
            #pragma unroll
            for (int off = 32; off > 0; off >>= 1)
                m = fmaxf(m, __shfl_xor(m, off));
            const float e = expf(s - m);
            float sum = e;
            #pragma unroll
            for (int off = 32; off > 0; off >>= 1)
                sum += __shfl_xor(sum, off);
            float v = (e / sum) * xtf[rw * 68 + lane];
            #pragma unroll
            for (int off = 32; off > 0; off >>= 1)
                v += __shfl_xor(v, off);
            const float diff = v - labpf[rr];   // same value on all lanes
            partial = fmaf(diff, diff, partial);
        }
        if (lane == 0)
            partials[blockIdx.x * 4 + w] = partial;   // private slot, no atomic
    }
}

extern "C" void kernel_launch(void* const* d_in, const int* in_sizes, int n_in,
                              void* d_out, int out_size, void* d_ws, size_t ws_size,
                              hipStream_t stream) {
    const float* x      = (const float*)d_in[0];
    const float* label  = (const float*)d_in[1];
    const float* u      = (const float*)d_in[2];
    const float* W1     = (const float*)d_in[3];
    const float* b1     = (const float*)d_in[4];
    const float* W2     = (const float*)d_in[5];
    const float* b2     = (const float*)d_in[6];
    const float* W3     = (const float*)d_in[7];
    const float* b3     = (const float*)d_in[8];
    const float* thetas = (const float*)d_in[9];
    const int*   epoch  = (const int*)d_in[10];
    float* out = (float*)d_out;

    unsigned short* wsb = (unsigned short*)d_ws;
    float* partials = (float*)(wsb + 204800);    // byte offset 409600

    prep_k<<<800, 256, 0, stream>>>(W1, W2, W3, thetas, wsb);
    llp_mfma<<<Bn / BM, 256, 0, stream>>>(x, label, u, b1, b2, b3,
                                          wsb, wsb + 131072, wsb + 163840, wsb + 196608,
                                          epoch, partials);
    reduce_k<<<1, 1024, 0, stream>>>(partials, out);
}